// Round 17
// baseline (70.225 us; speedup 1.0000x reference)
//
#include <hip/hip_runtime.h>
#include <hip/hip_bf16.h>

// Problem constants
#define B_   32
#define LLT  1024
#define LRT  1024
#define H_   256
#define A_   128

typedef __attribute__((ext_vector_type(8))) short  short8;
typedef __attribute__((ext_vector_type(4))) short  short4v;
typedef __attribute__((ext_vector_type(4))) float  f32x4;
typedef __bf16 bf16x8 __attribute__((ext_vector_type(8)));

static __device__ __forceinline__ unsigned short f2bf(float f) {
    return __builtin_bit_cast(unsigned short, (__bf16)f);   // native cvt, RNE
}

static __device__ __forceinline__ bf16x8 ld_bf8(const unsigned short* p) {
    return __builtin_bit_cast(bf16x8, *reinterpret_cast<const short8*>(p));
}

// fast tanh: (e^2x - 1) / (e^2x + 1); rel err ~1e-6, far below bf16 rounding
static __device__ __forceinline__ float fast_tanh(float x) {
    float cx = fminf(fmaxf(x, -15.f), 15.f);
    float e  = __expf(2.f * cx);
    return (e - 1.f) * __builtin_amdgcn_rcpf(e + 1.f);
}

// ---------------------------------------------------------------------------
// Kernel 0: attn_kernel [H][A] f32  ->  Kt [A][H] bf16 (transposed for frags)
// ---------------------------------------------------------------------------
__global__ void k_prep(const float* __restrict__ K, unsigned short* __restrict__ Kt) {
    int i = blockIdx.x * 256 + threadIdx.x;       // i in [0, A_*H_)
    int a = i >> 8;                               // / H_
    int h = i & (H_ - 1);
    Kt[i] = f2bf(K[h * A_ + a]);
}

// ---------------------------------------------------------------------------
// Kernel A: rt-only projection  [32768,256] @ [256,128] -> tanh -> bf16
// grid 256. block = 256 (4 waves). FULLY WAVE-PRIVATE (zero barriers).
// Rotate-1 LDS swizzles throughout (round-15 verified).
// ---------------------------------------------------------------------------
__global__ __launch_bounds__(256) void k_proj_rt(
        const float* __restrict__ reps_rt, const unsigned short* __restrict__ Kt,
        unsigned short* __restrict__ rt_bf) {
    const int tid  = threadIdx.x;
    const int wave = tid >> 6, lane = tid & 63;
    const int g = lane >> 4, r0 = lane & 15;
    const int blockRow0 = blockIdx.x * 128;

    __shared__ unsigned short T[128 * 256];       // 64 KB, wave-private regions

    const int kb   = lane & 31;
    const int rsel = lane >> 5;                   // 0..1
    #pragma unroll 4
    for (int it = 0; it < 16; ++it) {
        int row_l = wave * 32 + it * 2 + rsel;
        const float* p = reps_rt + (size_t)(blockRow0 + row_l) * H_ + kb * 8;
        float4 x0 = *reinterpret_cast<const float4*>(p);
        float4 x1 = *reinterpret_cast<const float4*>(p + 4);
        short8 t;
        t[0] = (short)f2bf(x0.x); t[1] = (short)f2bf(x0.y);
        t[2] = (short)f2bf(x0.z); t[3] = (short)f2bf(x0.w);
        t[4] = (short)f2bf(x1.x); t[5] = (short)f2bf(x1.y);
        t[6] = (short)f2bf(x1.z); t[7] = (short)f2bf(x1.w);
        int s = (kb + row_l) & 31;                // rotate-1
        *reinterpret_cast<short8*>(&T[row_l * 256 + s * 8]) = t;
    }

    f32x4 zero = {0.f, 0.f, 0.f, 0.f};
    f32x4 acc[8][2];
    #pragma unroll
    for (int c = 0; c < 8; ++c) { acc[c][0] = zero; acc[c][1] = zero; }

    #pragma unroll
    for (int ks = 0; ks < 8; ++ks) {
        bf16x8 br[2];
        #pragma unroll
        for (int mr = 0; mr < 2; ++mr) {
            int row_l = wave * 32 + mr * 16 + r0;
            int s = (4 * ks + g + row_l) & 31;    // rotate-1
            br[mr] = ld_bf8(&T[row_l * 256 + s * 8]);
        }
        #pragma unroll
        for (int c = 0; c < 8; ++c) {
            bf16x8 ka = ld_bf8(Kt + (size_t)(c * 16 + r0) * H_ + ks * 32 + g * 8);
            acc[c][0] = __builtin_amdgcn_mfma_f32_16x16x32_bf16(ka, br[0], acc[c][0], 0, 0, 0);
            acc[c][1] = __builtin_amdgcn_mfma_f32_16x16x32_bf16(ka, br[1], acc[c][1], 0, 0, 0);
        }
    }

    #pragma unroll
    for (int c = 0; c < 8; ++c)
        #pragma unroll
        for (int mr = 0; mr < 2; ++mr) {
            int row_l = wave * 32 + mr * 16 + r0;
            short4v o;
            #pragma unroll
            for (int r = 0; r < 4; ++r)
                o[r] = (short)f2bf(fast_tanh(acc[c][mr][r]));
            int phys = (4 * c + g + row_l) & 31;  // rotate-1
            *reinterpret_cast<short4v*>(&T[row_l * 256 + phys * 4]) = o;
        }

    #pragma unroll 4
    for (int it = 0; it < 16; ++it) {
        int row_l = wave * 32 + it * 2 + rsel;
        int gran  = lane & 31;
        int phys  = (gran + row_l) & 31;          // rotate-1
        short4v v = *reinterpret_cast<const short4v*>(&T[row_l * 256 + phys * 4]);
        *reinterpret_cast<short4v*>(rt_bf + (size_t)(blockRow0 + row_l) * A_ + gran * 4) = v;
    }
}

// ---------------------------------------------------------------------------
// Kernel B (fused): lt-projection + S = lt·rt^T + masks + softmax + store.
// grid 1024 (XCD-grouped). block = 512 (8 waves). Round-16 structure with
// DEPTH-2 KV pipeline spanning the proj phase: chunk-0/1 rt loads issue at
// kernel ENTRY (held in regs across proj — their latency hides under the
// ~15us proj phase), ds_write after the proj barrier; then a rolling
// issue(u+2) / compute(u) / write(u+2) pipeline (pfA/pfB static alternation,
// full unroll). In-order DS makes same-half reuse safe. Wave-private.
// ---------------------------------------------------------------------------
__global__ __launch_bounds__(512, 4) void k_attn(
        const float* __restrict__ reps_lt, const unsigned short* __restrict__ rt_bf,
        const unsigned short* __restrict__ Kt, const float* __restrict__ dW,
        const float* __restrict__ mask_lt, const float* __restrict__ mask_rt,
        float* __restrict__ out) {
    // XCD-aware decode: XCD = blk%8 (heuristic); XCD x serves batches 4x..4x+3.
    const int blk = blockIdx.x;
    const int b   = (blk & 7) * 4 + ((blk >> 3) & 3);
    const int m0  = (blk >> 5) * 32;

    const int tid = threadIdx.x;
    const int wave = tid >> 6, lane = tid & 63;
    const int g = lane >> 4, r0 = lane & 15;
    const int cb = wave * 128;

    __shared__ __align__(16) unsigned char SMEM[65536];       // LtStage | KV | P
    __shared__ __align__(16) unsigned short LtBf[32 * 128];   // 8 KB persistent
    __shared__ float red_sum[8][32];
    unsigned short* KVp     = (unsigned short*)SMEM + wave * 4096;  // 8 KB/wave
    unsigned short* LtStage = (unsigned short*)SMEM;                // 16 KB alias

    const unsigned short* __restrict__ rtb = rt_bf + (size_t)b * LRT * A_;
    const int rsub = lane >> 4;                   // 0..3
    const int gnat = lane & 15;                   // 16-B granule in row

    // ---- EARLY ISSUE: chunk-0/1 rt loads + mask_lt (hide under proj) ----
    short8 pfA[4], pfB[4];
    #pragma unroll
    for (int it = 0; it < 4; ++it) {
        int rr = it * 4 + rsub;
        pfA[it] = *reinterpret_cast<const short8*>(
            rtb + (size_t)(cb + rr) * A_ + gnat * 8);
        pfB[it] = *reinterpret_cast<const short8*>(
            rtb + (size_t)(cb + 16 + rr) * A_ + gnat * 8);
    }
    float mlt[2];
    #pragma unroll
    for (int mr = 0; mr < 2; ++mr)
        mlt[mr] = mask_lt[(size_t)b * LLT + m0 + mr * 16 + r0];

    // ---- phase 0: stage reps_lt rows m0..m0+31 -> bf16 LtStage, swizzled ----
    {
        const float* srcb = reps_lt + ((size_t)b * LLT + m0) * H_;
        int nat = tid & 31;                       // 16-B granule in row (0..31)
        #pragma unroll
        for (int it = 0; it < 2; ++it) {
            int row_l = (tid >> 5) + it * 16;
            const float* p = srcb + (size_t)row_l * H_ + nat * 8;
            float4 x0 = *reinterpret_cast<const float4*>(p);
            float4 x1 = *reinterpret_cast<const float4*>(p + 4);
            short8 t;
            t[0] = (short)f2bf(x0.x); t[1] = (short)f2bf(x0.y);
            t[2] = (short)f2bf(x0.z); t[3] = (short)f2bf(x0.w);
            t[4] = (short)f2bf(x1.x); t[5] = (short)f2bf(x1.y);
            t[6] = (short)f2bf(x1.z); t[7] = (short)f2bf(x1.w);
            int phys = (nat + row_l) & 31;        // rotate-1
            *reinterpret_cast<short8*>(&LtStage[row_l * 256 + phys * 8]) = t;
        }
    }
    __syncthreads();

    // ---- phase 1: proj GEMM — wave computes lt cols wave*16..wave*16+15 ----
    {
        f32x4 zero = {0.f, 0.f, 0.f, 0.f};
        f32x4 pacc[2];
        pacc[0] = zero; pacc[1] = zero;
        #pragma unroll
        for (int ks = 0; ks < 8; ++ks) {
            bf16x8 br[2];
            #pragma unroll
            for (int mr = 0; mr < 2; ++mr) {
                int row_l = mr * 16 + r0;
                int s = (4 * ks + g + row_l) & 31;    // rotate-1
                br[mr] = ld_bf8(&LtStage[row_l * 256 + s * 8]);
            }
            bf16x8 ka = ld_bf8(Kt + (size_t)(wave * 16 + r0) * H_ + ks * 32 + g * 8);
            pacc[0] = __builtin_amdgcn_mfma_f32_16x16x32_bf16(ka, br[0], pacc[0], 0, 0, 0);
            pacc[1] = __builtin_amdgcn_mfma_f32_16x16x32_bf16(ka, br[1], pacc[1], 0, 0, 0);
        }
        // epilogue: tanh * dW -> bf16 -> LtBf (rotate-1)
        f32x4 w4 = *reinterpret_cast<const f32x4*>(dW + wave * 16 + 4 * g);
        int h8 = 4 * wave + g;                    // 8-B granule index (0..31)
        #pragma unroll
        for (int mr = 0; mr < 2; ++mr) {
            int row = mr * 16 + r0;               // lane&15 = row
            short4v o;
            #pragma unroll
            for (int r = 0; r < 4; ++r)
                o[r] = (short)f2bf(fast_tanh(pacc[mr][r]) * w4[r]);
            int phys16 = ((h8 >> 1) + row) & 15;
            *reinterpret_cast<short4v*>(&LtBf[row * 128 + phys16 * 8 + (h8 & 1) * 4]) = o;
        }
    }
    __syncthreads();   // LtBf complete; LtStage dead from here (KV may overwrite)

    // write pre-loaded chunks 0,1 into the ping-pong halves
    #pragma unroll
    for (int it = 0; it < 4; ++it) {
        int rr = it * 4 + rsub;
        int phys = (gnat + rr) & 15;              // rotate-1
        *reinterpret_cast<short8*>(&KVp[rr * 128 + phys * 8]) = pfA[it];
        *reinterpret_cast<short8*>(&KVp[2048 + rr * 128 + phys * 8]) = pfB[it];
    }

    // lt fragments from LtBf: row = mr*16+r0, nat16 = ks*4+g, phys = (nat+row)&15
    bf16x8 lb[2][4];
    #pragma unroll
    for (int mr = 0; mr < 2; ++mr)
        #pragma unroll
        for (int ks = 0; ks < 4; ++ks) {
            int row = mr * 16 + r0;
            int phys16 = (ks * 4 + g + row) & 15;
            lb[mr][ks] = ld_bf8(&LtBf[row * 128 + phys16 * 8]);
        }

    f32x4 zero = {0.f, 0.f, 0.f, 0.f};
    f32x4 acc[8][2];
    #pragma unroll
    for (int c = 0; c < 8; ++c) { acc[c][0] = zero; acc[c][1] = zero; }

    // ---- phase 2: depth-2 rolling pipeline over 8 chunks of 16 rt rows ----
    #pragma unroll
    for (int u = 0; u < 8; ++u) {
        // issue-early: chunk u+2 global loads (pfA/pfB static alternation)
        if (u < 6) {
            #pragma unroll
            for (int it = 0; it < 4; ++it) {
                int rr = it * 4 + rsub;
                short8 v = *reinterpret_cast<const short8*>(
                    rtb + (size_t)(cb + (u + 2) * 16 + rr) * A_ + gnat * 8);
                if ((u & 1) == 0) pfA[it] = v; else pfB[it] = v;
            }
        }
        // compute chunk u (col-tile u) from half u&1
        const unsigned short* half = KVp + (u & 1) * 2048;
        __builtin_amdgcn_s_setprio(1);
        #pragma unroll
        for (int ks = 0; ks < 4; ++ks) {
            int gphy = (ks * 4 + g + r0) & 15;    // rotate-1, rows 0..15
            bf16x8 ra = ld_bf8(half + r0 * 128 + gphy * 8);
            acc[u][0] = __builtin_amdgcn_mfma_f32_16x16x32_bf16(ra, lb[0][ks], acc[u][0], 0, 0, 0);
            acc[u][1] = __builtin_amdgcn_mfma_f32_16x16x32_bf16(ra, lb[1][ks], acc[u][1], 0, 0, 0);
        }
        __builtin_amdgcn_s_setprio(0);
        // write-late: chunk u+2 into half u&1 (after u's reads — in-order DS)
        if (u < 6) {
            unsigned short* half2 = KVp + (u & 1) * 2048;
            #pragma unroll
            for (int it = 0; it < 4; ++it) {
                int rr = it * 4 + rsub;
                int phys = (gnat + rr) & 15;      // rotate-1
                short8 v = ((u & 1) == 0) ? pfA[it] : pfB[it];
                *reinterpret_cast<short8*>(&half2[rr * 128 + phys * 8]) = v;
            }
        }
    }

    // exp (no max pass: logits bounded by tanh outputs; clamp for safety) + sums
    float rsum[2];
    rsum[0] = 0.f; rsum[1] = 0.f;
    #pragma unroll
    for (int c = 0; c < 8; ++c) {
        f32x4 m4 = *reinterpret_cast<const f32x4*>(mask_rt + (size_t)b * LRT + cb + c * 16 + 4 * g);
        #pragma unroll
        for (int mr = 0; mr < 2; ++mr)
            #pragma unroll
            for (int r = 0; r < 4; ++r) {
                float v = acc[c][mr][r] * (mlt[mr] * m4[r]);
                float e = __expf(fminf(v, 60.f));
                acc[c][mr][r] = e * m4[r];        // post-softmax rt-mask folded in
                rsum[mr] += e;
            }
    }
    #pragma unroll
    for (int mr = 0; mr < 2; ++mr) {
        float s = rsum[mr];
        s += __shfl_xor(s, 16, 64);
        s += __shfl_xor(s, 32, 64);
        rsum[mr] = s;
    }
    if (g == 0) {
        red_sum[wave][r0]      = rsum[0];
        red_sum[wave][16 + r0] = rsum[1];
    }
    __syncthreads();          // also orders: all KV reads above / P writes below
    float sc[2];
    #pragma unroll
    for (int mr = 0; mr < 2; ++mr) {
        int rl = mr * 16 + r0;
        float s = red_sum[0][rl];
        #pragma unroll
        for (int w = 1; w < 8; ++w) s += red_sum[w][rl];
        sc[mr] = mlt[mr] * __builtin_amdgcn_rcpf(s);  // post-softmax lt-mask folded in
    }

    // epilogue: 2 phases of 16 rows through the reused 64-KB buffer (rotate-1)
    float* P_lds = (float*)SMEM;
    #pragma unroll
    for (int mr = 0; mr < 2; ++mr) {
        #pragma unroll
        for (int c = 0; c < 8; ++c) {
            f32x4 o;
            #pragma unroll
            for (int r = 0; r < 4; ++r) o[r] = acc[c][mr][r] * sc[mr];
            int col16 = wave * 32 + 4 * c + g;            // natural granule 0..255
            int gran  = (col16 + r0) & 255;               // rotate-1
            *reinterpret_cast<f32x4*>(&P_lds[r0 * 1024 + gran * 4]) = o;
        }
        __syncthreads();
        #pragma unroll
        for (int i = 0; i < 2; ++i) {
            int row_l = 2 * wave + i;
            float* op = out + ((size_t)b * LLT + m0 + mr * 16 + row_l) * LRT;
            #pragma unroll
            for (int seg = 0; seg < 4; ++seg) {
                int gran = (lane + 64 * seg + row_l) & 255;   // rotate-1
                f32x4 v = *reinterpret_cast<const f32x4*>(&P_lds[row_l * 1024 + gran * 4]);
                *reinterpret_cast<f32x4*>(op + seg * 256 + lane * 4) = v;
            }
        }
        __syncthreads();
    }
}

// ---------------------------------------------------------------------------
extern "C" void kernel_launch(void* const* d_in, const int* in_sizes, int n_in,
                              void* d_out, int out_size, void* d_ws, size_t ws_size,
                              hipStream_t stream) {
    const float* reps_lt = (const float*)d_in[0];
    const float* reps_rt = (const float*)d_in[1];
    const float* mask_lt = (const float*)d_in[2];
    const float* mask_rt = (const float*)d_in[3];
    const float* attn_k  = (const float*)d_in[4];
    const float* diagW   = (const float*)d_in[5];
    float* out = (float*)d_out;

    // workspace layout (bf16 as ushort bits)
    unsigned short* Kt  = (unsigned short*)d_ws;                // [A][H]   64 KB
    unsigned short* rtb = Kt + (size_t)A_ * H_;                 // [B*LRT][A]  8 MB

    k_prep<<<dim3((A_ * H_) / 256), dim3(256), 0, stream>>>(attn_k, Kt);
    k_proj_rt<<<dim3((B_ * LRT) / 128), dim3(256), 0, stream>>>(reps_rt, Kt, rtb);
    k_attn<<<dim3(LLT / 32 * B_), dim3(512), 0, stream>>>(
        reps_lt, rtb, Kt, diagW, mask_lt, mask_rt, out);
}

// Round 18
// 67.799 us; speedup vs baseline: 1.0358x; 1.0358x over previous
//
#include <hip/hip_runtime.h>
#include <hip/hip_bf16.h>

// Problem constants
#define B_   32
#define LLT  1024
#define LRT  1024
#define H_   256
#define A_   128

typedef __attribute__((ext_vector_type(8))) short  short8;
typedef __attribute__((ext_vector_type(4))) short  short4v;
typedef __attribute__((ext_vector_type(4))) float  f32x4;
typedef __bf16 bf16x8 __attribute__((ext_vector_type(8)));

static __device__ __forceinline__ unsigned short f2bf(float f) {
    return __builtin_bit_cast(unsigned short, (__bf16)f);   // native cvt, RNE
}

static __device__ __forceinline__ bf16x8 ld_bf8(const unsigned short* p) {
    return __builtin_bit_cast(bf16x8, *reinterpret_cast<const short8*>(p));
}

// fast tanh: (e^2x - 1) / (e^2x + 1); rel err ~1e-6, far below bf16 rounding
static __device__ __forceinline__ float fast_tanh(float x) {
    float cx = fminf(fmaxf(x, -15.f), 15.f);
    float e  = __expf(2.f * cx);
    return (e - 1.f) * __builtin_amdgcn_rcpf(e + 1.f);
}

// ---------------------------------------------------------------------------
// Kernel 0: attn_kernel [H][A] f32  ->  Kt [A][H] bf16 (transposed for frags)
// ---------------------------------------------------------------------------
__global__ void k_prep(const float* __restrict__ K, unsigned short* __restrict__ Kt) {
    int i = blockIdx.x * 256 + threadIdx.x;       // i in [0, A_*H_)
    int a = i >> 8;                               // / H_
    int h = i & (H_ - 1);
    Kt[i] = f2bf(K[h * A_ + a]);
}

// ---------------------------------------------------------------------------
// Kernel A: rt-only projection  [32768,256] @ [256,128] -> tanh -> bf16
// grid 256. block = 256 (4 waves). FULLY WAVE-PRIVATE (zero barriers).
// Rotate-1 LDS swizzles throughout (round-15 verified).
// ---------------------------------------------------------------------------
__global__ __launch_bounds__(256) void k_proj_rt(
        const float* __restrict__ reps_rt, const unsigned short* __restrict__ Kt,
        unsigned short* __restrict__ rt_bf) {
    const int tid  = threadIdx.x;
    const int wave = tid >> 6, lane = tid & 63;
    const int g = lane >> 4, r0 = lane & 15;
    const int blockRow0 = blockIdx.x * 128;

    __shared__ unsigned short T[128 * 256];       // 64 KB, wave-private regions

    const int kb   = lane & 31;
    const int rsel = lane >> 5;                   // 0..1
    #pragma unroll 4
    for (int it = 0; it < 16; ++it) {
        int row_l = wave * 32 + it * 2 + rsel;
        const float* p = reps_rt + (size_t)(blockRow0 + row_l) * H_ + kb * 8;
        float4 x0 = *reinterpret_cast<const float4*>(p);
        float4 x1 = *reinterpret_cast<const float4*>(p + 4);
        short8 t;
        t[0] = (short)f2bf(x0.x); t[1] = (short)f2bf(x0.y);
        t[2] = (short)f2bf(x0.z); t[3] = (short)f2bf(x0.w);
        t[4] = (short)f2bf(x1.x); t[5] = (short)f2bf(x1.y);
        t[6] = (short)f2bf(x1.z); t[7] = (short)f2bf(x1.w);
        int s = (kb + row_l) & 31;                // rotate-1
        *reinterpret_cast<short8*>(&T[row_l * 256 + s * 8]) = t;
    }

    f32x4 zero = {0.f, 0.f, 0.f, 0.f};
    f32x4 acc[8][2];
    #pragma unroll
    for (int c = 0; c < 8; ++c) { acc[c][0] = zero; acc[c][1] = zero; }

    #pragma unroll
    for (int ks = 0; ks < 8; ++ks) {
        bf16x8 br[2];
        #pragma unroll
        for (int mr = 0; mr < 2; ++mr) {
            int row_l = wave * 32 + mr * 16 + r0;
            int s = (4 * ks + g + row_l) & 31;    // rotate-1
            br[mr] = ld_bf8(&T[row_l * 256 + s * 8]);
        }
        #pragma unroll
        for (int c = 0; c < 8; ++c) {
            bf16x8 ka = ld_bf8(Kt + (size_t)(c * 16 + r0) * H_ + ks * 32 + g * 8);
            acc[c][0] = __builtin_amdgcn_mfma_f32_16x16x32_bf16(ka, br[0], acc[c][0], 0, 0, 0);
            acc[c][1] = __builtin_amdgcn_mfma_f32_16x16x32_bf16(ka, br[1], acc[c][1], 0, 0, 0);
        }
    }

    #pragma unroll
    for (int c = 0; c < 8; ++c)
        #pragma unroll
        for (int mr = 0; mr < 2; ++mr) {
            int row_l = wave * 32 + mr * 16 + r0;
            short4v o;
            #pragma unroll
            for (int r = 0; r < 4; ++r)
                o[r] = (short)f2bf(fast_tanh(acc[c][mr][r]));
            int phys = (4 * c + g + row_l) & 31;  // rotate-1
            *reinterpret_cast<short4v*>(&T[row_l * 256 + phys * 4]) = o;
        }

    #pragma unroll 4
    for (int it = 0; it < 16; ++it) {
        int row_l = wave * 32 + it * 2 + rsel;
        int gran  = lane & 31;
        int phys  = (gran + row_l) & 31;          // rotate-1
        short4v v = *reinterpret_cast<const short4v*>(&T[row_l * 256 + phys * 4]);
        *reinterpret_cast<short4v*>(rt_bf + (size_t)(blockRow0 + row_l) * A_ + gran * 4) = v;
    }
}

// ---------------------------------------------------------------------------
// Kernel B (fused): lt-projection + S = lt·rt^T + masks + softmax + store.
// grid 1024 (XCD-grouped). block = 512 (8 waves). Best-verified structure
// (round 16, 68.25us): shallow T14 async-stage — 8 sub-chunks of 16 rt rows,
// register prefetch (issue-early) + LDS ping-pong 2x4KB/wave (write-late).
// The MFMA cluster of chunk u sits between chunk u+1's load-issue and
// load-use. Wave-private, zero barriers in the main loop.
// Depth-2 variant (round 17) REGRESSED: in-order vmcnt forces early loads
// to drain before phase-0's conversions anyway, and 16 VGPRs of prefetch
// held across the proj phase tighten regalloc. Do not deepen.
// ---------------------------------------------------------------------------
__global__ __launch_bounds__(512, 4) void k_attn(
        const float* __restrict__ reps_lt, const unsigned short* __restrict__ rt_bf,
        const unsigned short* __restrict__ Kt, const float* __restrict__ dW,
        const float* __restrict__ mask_lt, const float* __restrict__ mask_rt,
        float* __restrict__ out) {
    // XCD-aware decode: XCD = blk%8 (heuristic); XCD x serves batches 4x..4x+3.
    const int blk = blockIdx.x;
    const int b   = (blk & 7) * 4 + ((blk >> 3) & 3);
    const int m0  = (blk >> 5) * 32;

    const int tid = threadIdx.x;
    const int wave = tid >> 6, lane = tid & 63;
    const int g = lane >> 4, r0 = lane & 15;
    const int cb = wave * 128;

    __shared__ __align__(16) unsigned char SMEM[65536];       // LtStage | KV | P
    __shared__ __align__(16) unsigned short LtBf[32 * 128];   // 8 KB persistent
    __shared__ float red_sum[8][32];
    unsigned short* KVp     = (unsigned short*)SMEM + wave * 4096;  // 8 KB/wave
    unsigned short* LtStage = (unsigned short*)SMEM;                // 16 KB alias

    const unsigned short* __restrict__ rtb = rt_bf + (size_t)b * LRT * A_;

    // ---- phase 0: stage reps_lt rows m0..m0+31 -> bf16 LtStage, swizzled ----
    {
        const float* srcb = reps_lt + ((size_t)b * LLT + m0) * H_;
        int nat = tid & 31;                       // 16-B granule in row (0..31)
        #pragma unroll
        for (int it = 0; it < 2; ++it) {
            int row_l = (tid >> 5) + it * 16;
            const float* p = srcb + (size_t)row_l * H_ + nat * 8;
            float4 x0 = *reinterpret_cast<const float4*>(p);
            float4 x1 = *reinterpret_cast<const float4*>(p + 4);
            short8 t;
            t[0] = (short)f2bf(x0.x); t[1] = (short)f2bf(x0.y);
            t[2] = (short)f2bf(x0.z); t[3] = (short)f2bf(x0.w);
            t[4] = (short)f2bf(x1.x); t[5] = (short)f2bf(x1.y);
            t[6] = (short)f2bf(x1.z); t[7] = (short)f2bf(x1.w);
            int phys = (nat + row_l) & 31;        // rotate-1
            *reinterpret_cast<short8*>(&LtStage[row_l * 256 + phys * 8]) = t;
        }
    }
    __syncthreads();

    // ---- phase 1: proj GEMM — wave computes lt cols wave*16..wave*16+15 ----
    {
        f32x4 zero = {0.f, 0.f, 0.f, 0.f};
        f32x4 pacc[2];
        pacc[0] = zero; pacc[1] = zero;
        #pragma unroll
        for (int ks = 0; ks < 8; ++ks) {
            bf16x8 br[2];
            #pragma unroll
            for (int mr = 0; mr < 2; ++mr) {
                int row_l = mr * 16 + r0;
                int s = (4 * ks + g + row_l) & 31;    // rotate-1
                br[mr] = ld_bf8(&LtStage[row_l * 256 + s * 8]);
            }
            bf16x8 ka = ld_bf8(Kt + (size_t)(wave * 16 + r0) * H_ + ks * 32 + g * 8);
            pacc[0] = __builtin_amdgcn_mfma_f32_16x16x32_bf16(ka, br[0], pacc[0], 0, 0, 0);
            pacc[1] = __builtin_amdgcn_mfma_f32_16x16x32_bf16(ka, br[1], pacc[1], 0, 0, 0);
        }
        // epilogue: tanh * dW -> bf16 -> LtBf (rotate-1)
        f32x4 w4 = *reinterpret_cast<const f32x4*>(dW + wave * 16 + 4 * g);
        int h8 = 4 * wave + g;                    // 8-B granule index (0..31)
        #pragma unroll
        for (int mr = 0; mr < 2; ++mr) {
            int row = mr * 16 + r0;               // lane&15 = row
            short4v o;
            #pragma unroll
            for (int r = 0; r < 4; ++r)
                o[r] = (short)f2bf(fast_tanh(pacc[mr][r]) * w4[r]);
            int phys16 = ((h8 >> 1) + row) & 15;
            *reinterpret_cast<short4v*>(&LtBf[row * 128 + phys16 * 8 + (h8 & 1) * 4]) = o;
        }
    }
    __syncthreads();   // LtBf complete; LtStage dead from here (KV may overwrite)

    // lt fragments from LtBf: row = mr*16+r0, nat16 = ks*4+g, phys = (nat+row)&15
    bf16x8 lb[2][4];
    #pragma unroll
    for (int mr = 0; mr < 2; ++mr)
        #pragma unroll
        for (int ks = 0; ks < 4; ++ks) {
            int row = mr * 16 + r0;
            int phys16 = (ks * 4 + g + row) & 15;
            lb[mr][ks] = ld_bf8(&LtBf[row * 128 + phys16 * 8]);
        }

    f32x4 zero = {0.f, 0.f, 0.f, 0.f};
    f32x4 acc[8][2];
    #pragma unroll
    for (int c = 0; c < 8; ++c) { acc[c][0] = zero; acc[c][1] = zero; }

    // ---- phase 2: 8 sub-chunks of 16 rt rows, prefetch + ping-pong (T14) ----
    {
        const int rsub = lane >> 4;               // 0..3
        const int gnat = lane & 15;               // 16-B granule in row
        short8 pf[4];
        // prologue: load + write chunk 0 into half 0
        #pragma unroll
        for (int it = 0; it < 4; ++it) {
            int rr = it * 4 + rsub;
            pf[it] = *reinterpret_cast<const short8*>(
                rtb + (size_t)(cb + rr) * A_ + gnat * 8);
        }
        #pragma unroll
        for (int it = 0; it < 4; ++it) {
            int rr = it * 4 + rsub;
            int phys = (gnat + rr) & 15;          // rotate-1
            *reinterpret_cast<short8*>(&KVp[rr * 128 + phys * 8]) = pf[it];
        }
        #pragma unroll
        for (int u = 0; u < 8; ++u) {
            // issue-early: chunk u+1 global loads (latency hides under MFMAs)
            if (u < 7) {
                #pragma unroll
                for (int it = 0; it < 4; ++it) {
                    int rr = it * 4 + rsub;
                    pf[it] = *reinterpret_cast<const short8*>(
                        rtb + (size_t)(cb + (u + 1) * 16 + rr) * A_ + gnat * 8);
                }
            }
            // compute chunk u (col-tile u) from half u&1
            const unsigned short* half = KVp + (u & 1) * 2048;
            __builtin_amdgcn_s_setprio(1);
            #pragma unroll
            for (int ks = 0; ks < 4; ++ks) {
                int gphy = (ks * 4 + g + r0) & 15;    // rotate-1, rows 0..15
                bf16x8 ra = ld_bf8(half + r0 * 128 + gphy * 8);
                acc[u][0] = __builtin_amdgcn_mfma_f32_16x16x32_bf16(ra, lb[0][ks], acc[u][0], 0, 0, 0);
                acc[u][1] = __builtin_amdgcn_mfma_f32_16x16x32_bf16(ra, lb[1][ks], acc[u][1], 0, 0, 0);
            }
            __builtin_amdgcn_s_setprio(0);
            // write-late: chunk u+1 into the other half (no conflict with reads)
            if (u < 7) {
                unsigned short* half2 = KVp + ((u + 1) & 1) * 2048;
                #pragma unroll
                for (int it = 0; it < 4; ++it) {
                    int rr = it * 4 + rsub;
                    int phys = (gnat + rr) & 15;  // rotate-1
                    *reinterpret_cast<short8*>(&half2[rr * 128 + phys * 8]) = pf[it];
                }
            }
        }
    }

    // masks
    float mlt[2];
    #pragma unroll
    for (int mr = 0; mr < 2; ++mr)
        mlt[mr] = mask_lt[(size_t)b * LLT + m0 + mr * 16 + r0];

    // exp (no max pass: logits bounded by tanh outputs; clamp for safety) + sums
    float rsum[2];
    rsum[0] = 0.f; rsum[1] = 0.f;
    #pragma unroll
    for (int c = 0; c < 8; ++c) {
        f32x4 m4 = *reinterpret_cast<const f32x4*>(mask_rt + (size_t)b * LRT + cb + c * 16 + 4 * g);
        #pragma unroll
        for (int mr = 0; mr < 2; ++mr)
            #pragma unroll
            for (int r = 0; r < 4; ++r) {
                float v = acc[c][mr][r] * (mlt[mr] * m4[r]);
                float e = __expf(fminf(v, 60.f));
                acc[c][mr][r] = e * m4[r];        // post-softmax rt-mask folded in
                rsum[mr] += e;
            }
    }
    #pragma unroll
    for (int mr = 0; mr < 2; ++mr) {
        float s = rsum[mr];
        s += __shfl_xor(s, 16, 64);
        s += __shfl_xor(s, 32, 64);
        rsum[mr] = s;
    }
    if (g == 0) {
        red_sum[wave][r0]      = rsum[0];
        red_sum[wave][16 + r0] = rsum[1];
    }
    __syncthreads();          // also orders: all KV reads above / P writes below
    float sc[2];
    #pragma unroll
    for (int mr = 0; mr < 2; ++mr) {
        int rl = mr * 16 + r0;
        float s = red_sum[0][rl];
        #pragma unroll
        for (int w = 1; w < 8; ++w) s += red_sum[w][rl];
        sc[mr] = mlt[mr] * __builtin_amdgcn_rcpf(s);  // post-softmax lt-mask folded in
    }

    // epilogue: 2 phases of 16 rows through the reused 64-KB buffer (rotate-1)
    float* P_lds = (float*)SMEM;
    #pragma unroll
    for (int mr = 0; mr < 2; ++mr) {
        #pragma unroll
        for (int c = 0; c < 8; ++c) {
            f32x4 o;
            #pragma unroll
            for (int r = 0; r < 4; ++r) o[r] = acc[c][mr][r] * sc[mr];
            int col16 = wave * 32 + 4 * c + g;            // natural granule 0..255
            int gran  = (col16 + r0) & 255;               // rotate-1
            *reinterpret_cast<f32x4*>(&P_lds[r0 * 1024 + gran * 4]) = o;
        }
        __syncthreads();
        #pragma unroll
        for (int i = 0; i < 2; ++i) {
            int row_l = 2 * wave + i;
            float* op = out + ((size_t)b * LLT + m0 + mr * 16 + row_l) * LRT;
            #pragma unroll
            for (int seg = 0; seg < 4; ++seg) {
                int gran = (lane + 64 * seg + row_l) & 255;   // rotate-1
                f32x4 v = *reinterpret_cast<const f32x4*>(&P_lds[row_l * 1024 + gran * 4]);
                *reinterpret_cast<f32x4*>(op + seg * 256 + lane * 4) = v;
            }
        }
        __syncthreads();
    }
}

// ---------------------------------------------------------------------------
extern "C" void kernel_launch(void* const* d_in, const int* in_sizes, int n_in,
                              void* d_out, int out_size, void* d_ws, size_t ws_size,
                              hipStream_t stream) {
    const float* reps_lt = (const float*)d_in[0];
    const float* reps_rt = (const float*)d_in[1];
    const float* mask_lt = (const float*)d_in[2];
    const float* mask_rt = (const float*)d_in[3];
    const float* attn_k  = (const float*)d_in[4];
    const float* diagW   = (const float*)d_in[5];
    float* out = (float*)d_out;

    // workspace layout (bf16 as ushort bits)
    unsigned short* Kt  = (unsigned short*)d_ws;                // [A][H]   64 KB
    unsigned short* rtb = Kt + (size_t)A_ * H_;                 // [B*LRT][A]  8 MB

    k_prep<<<dim3((A_ * H_) / 256), dim3(256), 0, stream>>>(attn_k, Kt);
    k_proj_rt<<<dim3((B_ * LRT) / 128), dim3(256), 0, stream>>>(reps_rt, Kt, rtb);
    k_attn<<<dim3(LLT / 32 * B_), dim3(512), 0, stream>>>(
        reps_lt, rtb, Kt, diagW, mask_lt, mask_rt, out);
}